// Round 4
// baseline (6201.073 us; speedup 1.0000x reference)
//
#include <hip/hip_runtime.h>
#include <hip/hip_bf16.h>

#define QLEN 128
#define WOUT 32
#define PI_F 3.14159265358979f

// ---- bias/small-weight LDS offsets (floats) ----
#define OFF_BF    0      // 256
#define OFF_BIH   256    // 768
#define OFF_BHH   1024   // 768
#define OFF_LNG   1792   // 256
#define OFF_LNB   2048   // 256
#define OFF_BG    2304   // 64
#define OFF_BRP   2368   // 2
#define OFF_BIHR  2370   // 768
#define OFF_BHHR  3138   // 768
#define OFF_BRPR  3906   // 2
#define OFF_WRP   3908   // 512 (Wrp[2][256])
#define OFF_WRPR  4420   // 512
#define SB_TOTAL  4932

__device__ __forceinline__ float sigm(float x){ return 1.0f/(1.0f + __expf(-x)); }
__device__ __forceinline__ float tanh_f(float x){ return 2.0f/(1.0f + __expf(-2.0f*x)) - 1.0f; }

// Repack f32 W[N][K] (row-major) -> f32 T[k/4][N][4] so a wave's float4 weight
// loads (lane -> consecutive col c) are fully coalesced.
__global__ void transpose_w(const float* __restrict__ src, float* __restrict__ dst, int N, int K){
  int i = blockIdx.x*blockDim.x + threadIdx.x;
  if (i < N*K){
    int c = i / K; int k = i - c*K;
    dst[(size_t)(((k>>2)*N + c)<<2) + (k&3)] = src[i];
  }
}

__device__ __forceinline__ void fma4(float& acc, const float4& a, const float4& w){
  acc = fmaf(a.x, w.x, acc);
  acc = fmaf(a.y, w.y, acc);
  acc = fmaf(a.z, w.z, acc);
  acc = fmaf(a.w, w.w, acc);
}

__global__ __launch_bounds__(512) void knet_f32(
  const float* __restrict__ x_in,    // f32 [B][128][64]
  const float* __restrict__ t_wf,    // [48][256][4]
  const float* __restrict__ t_wih,   // [64][768][4]
  const float* __restrict__ t_whh,   // [64][768][4]
  const float* __restrict__ t_wg,    // [64][64][4]
  const float* __restrict__ t_wihr,  // [80][768][4]
  const float* __restrict__ t_whhr,  // [64][768][4]
  const float* __restrict__ p_bf,  const float* __restrict__ p_bih, const float* __restrict__ p_bhh,
  const float* __restrict__ p_lng, const float* __restrict__ p_lnb,
  const float* __restrict__ p_bg,  const float* __restrict__ p_wrp, const float* __restrict__ p_brp,
  const float* __restrict__ p_bihr,const float* __restrict__ p_bhhr,
  const float* __restrict__ p_wrpr,const float* __restrict__ p_brpr,
  float* __restrict__ out)           // f32 [B][32][64]
{
  __shared__ __align__(16) float sb[SB_TOTAL];
  __shared__ __align__(16) float s_h [8][260];   // post-LN h (fp32), padded to keep float4 row alignment
  __shared__ __align__(16) float s_pre[8][260];  // pre-LN GRU output
  __shared__ __align__(16) float s_zf[8][260];   // zf acts
  __shared__ __align__(16) float s_feat[8][196]; // feat acts (192 + pad)
  __shared__ __align__(16) float s_x[8][64];     // x_post / curr
  __shared__ __align__(16) float s_yt[2][8][64];
  __shared__ __align__(16) float s_upd[8][64];
  __shared__ __align__(16) float s_kg[8][64];
  __shared__ float s_rho[8], s_phi[8];

  const int tid = threadIdx.x;
  const int gb0 = blockIdx.x * 8;

  // ---- preload biases / tiny weights into LDS ----
  for (int i=tid;i<256;i+=512){ sb[OFF_BF+i]=p_bf[i]; sb[OFF_LNG+i]=p_lng[i]; sb[OFF_LNB+i]=p_lnb[i]; }
  for (int i=tid;i<768;i+=512){ sb[OFF_BIH+i]=p_bih[i]; sb[OFF_BHH+i]=p_bhh[i]; sb[OFF_BIHR+i]=p_bihr[i]; sb[OFF_BHHR+i]=p_bhhr[i]; }
  for (int i=tid;i<64;i+=512)  sb[OFF_BG+i]=p_bg[i];
  for (int i=tid;i<512;i+=512){ sb[OFF_WRP+i]=p_wrp[i]; sb[OFF_WRPR+i]=p_wrpr[i]; }
  if (tid<2){ sb[OFF_BRP+tid]=p_brp[tid]; sb[OFF_BRPR+tid]=p_brpr[tid]; }

  // ---- init state ----
  for (int e=tid; e<8*256; e+=512){ int r=e>>8, c=e&255; s_h[r][c]=0.f; }
  {
    int r = tid>>6, d = tid&63;  // 512 threads cover 8x64 exactly
    float y0 = x_in[(size_t)(gb0+r)*(QLEN*64) + d];
    s_x[r][d]=y0; s_yt[1][r][d]=y0; s_upd[r][d]=0.f;
  }
  __syncthreads();

  const int w    = tid >> 6;   // wave id 0..7
  const int lane = tid & 63;

  // LayerNorm + readout-proj (rho/phi). reads s_pre, writes s_h (normed), s_rho/s_phi.
  auto ln_rp = [&](int wrpO, int brpO){
    const int row = w;
    const int c0  = lane << 2;
    float4 v = *(const float4*)&s_pre[row][c0];
    float sum = v.x+v.y+v.z+v.w;
    float ss  = v.x*v.x + v.y*v.y + v.z*v.z + v.w*v.w;
    #pragma unroll
    for (int m=1;m<64;m<<=1){ sum += __shfl_xor(sum,m); ss += __shfl_xor(ss,m); }
    float mu = sum * (1.f/256.f);
    float rs = rsqrtf(ss*(1.f/256.f) - mu*mu + 1e-5f);
    float4 hn;
    hn.x = (v.x-mu)*rs*sb[OFF_LNG+c0  ] + sb[OFF_LNB+c0  ];
    hn.y = (v.y-mu)*rs*sb[OFF_LNG+c0+1] + sb[OFF_LNB+c0+1];
    hn.z = (v.z-mu)*rs*sb[OFF_LNG+c0+2] + sb[OFF_LNB+c0+2];
    hn.w = (v.w-mu)*rs*sb[OFF_LNG+c0+3] + sb[OFF_LNB+c0+3];
    *(float4*)&s_h[row][c0] = hn;
    float p0 = hn.x*sb[wrpO+c0] + hn.y*sb[wrpO+c0+1] + hn.z*sb[wrpO+c0+2] + hn.w*sb[wrpO+c0+3];
    float p1 = hn.x*sb[wrpO+256+c0] + hn.y*sb[wrpO+256+c0+1] + hn.z*sb[wrpO+256+c0+2] + hn.w*sb[wrpO+256+c0+3];
    #pragma unroll
    for (int m=1;m<64;m<<=1){ p0 += __shfl_xor(p0,m); p1 += __shfl_xor(p1,m); }
    if (lane==0){
      s_rho[row] = 1.25f * sigm(p0 + sb[brpO]);
      s_phi[row] = PI_F * tanh_f(p1 + sb[brpO+1]);
    }
  };

  // ======================= ENCODER: 128 steps =======================
  #pragma unroll 1
  for (int t=0; t<QLEN; ++t){
    const int cur = t & 1;

    // Phase A: load y_t, build feat (fp32)
    {
      int r = tid>>6, d = tid&63;
      float yv = x_in[(size_t)(gb0+r)*(QLEN*64) + (size_t)t*64 + d];
      s_yt[cur][r][d] = yv;
      s_feat[r][d]      = yv - s_yt[cur^1][r][d];
      s_feat[r][64+d]   = yv - s_x[r][d];
      s_feat[r][128+d]  = s_upd[r][d];
    }
    __syncthreads();

    // Phase B: zf = tanh(feat @ Wf^T + bf)   [8 x 256], K=192
    {
      const int j  = tid & 255;
      const int r0 = (tid >> 8) * 4;
      float acc[4] = {0.f,0.f,0.f,0.f};
      const float4* tf = (const float4*)t_wf;
      #pragma unroll 2
      for (int k4=0;k4<48;k4++){
        float4 wv = tf[k4*256 + j];
        #pragma unroll
        for (int ri=0;ri<4;ri++){
          float4 a = *(const float4*)&s_feat[r0+ri][k4<<2];
          fma4(acc[ri], a, wv);
        }
      }
      float bb = sb[OFF_BF + j];
      #pragma unroll
      for (int ri=0;ri<4;ri++) s_zf[r0+ri][j] = tanh_f(acc[ri] + bb);
    }
    __syncthreads();

    // Phase C: GRU gates + combine -> s_pre   (gi from zf, gh from h), K=256
    {
      const int j  = tid & 255;
      const int r0 = (tid >> 8) * 4;
      float a_ir[4]={0,0,0,0}, a_iz[4]={0,0,0,0}, a_in[4]={0,0,0,0};
      float a_hr[4]={0,0,0,0}, a_hz[4]={0,0,0,0}, a_hn[4]={0,0,0,0};
      const float4* tih = (const float4*)t_wih;
      const float4* thh = (const float4*)t_whh;
      #pragma unroll 2
      for (int k4=0;k4<64;k4++){
        float4 wir = tih[k4*768 +       j];
        float4 wiz = tih[k4*768 + 256 + j];
        float4 win = tih[k4*768 + 512 + j];
        float4 whr = thh[k4*768 +       j];
        float4 whz = thh[k4*768 + 256 + j];
        float4 whn = thh[k4*768 + 512 + j];
        #pragma unroll
        for (int ri=0;ri<4;ri++){
          float4 az = *(const float4*)&s_zf[r0+ri][k4<<2];
          float4 ah = *(const float4*)&s_h [r0+ri][k4<<2];
          fma4(a_ir[ri], az, wir);
          fma4(a_iz[ri], az, wiz);
          fma4(a_in[ri], az, win);
          fma4(a_hr[ri], ah, whr);
          fma4(a_hz[ri], ah, whz);
          fma4(a_hn[ri], ah, whn);
        }
      }
      float bir=sb[OFF_BIH+j], biz=sb[OFF_BIH+256+j], bin=sb[OFF_BIH+512+j];
      float bhr=sb[OFF_BHH+j], bhz=sb[OFF_BHH+256+j], bhn=sb[OFF_BHH+512+j];
      #pragma unroll
      for (int ri=0;ri<4;ri++){
        float r_ = sigm(a_ir[ri]+bir + a_hr[ri]+bhr);
        float z_ = sigm(a_iz[ri]+biz + a_hz[ri]+bhz);
        float n_ = tanh_f(a_in[ri]+bin + r_*(a_hn[ri]+bhn));
        s_pre[r0+ri][j] = (1.f - z_)*n_ + z_*s_h[r0+ri][j];
      }
    }
    __syncthreads();

    // Phase D: LayerNorm + rho/phi
    ln_rp(OFF_WRP, OFF_BRP);
    __syncthreads();

    // Phase E: K = sigmoid(h @ Wg^T + bg)  [8 x 64], K=256
    {
      const int j = tid & 63;
      const int r = tid >> 6;        // wave-uniform -> broadcast act reads
      float acc = 0.f;
      const float4* tg = (const float4*)t_wg;
      #pragma unroll 4
      for (int k4=0;k4<64;k4++){
        float4 wv = tg[k4*64 + j];
        float4 a  = *(const float4*)&s_h[r][k4<<2];
        fma4(acc, a, wv);
      }
      s_kg[r][j] = sigm(acc + sb[OFF_BG+j]);
    }
    __syncthreads();

    // Phase F: rotate prior + Kalman update
    if (tid < 256){
      int r = tid>>5, d = tid&31;
      float re = s_x[r][d], im = s_x[r][d+32];
      float rho = s_rho[r], phi = s_phi[r];
      float sn, cs; __sincosf(phi, &sn, &cs);
      float pre = rho*(cs*re - sn*im);
      float pim = rho*(sn*re + cs*im);
      float dre = s_kg[r][d]   * (s_yt[cur][r][d]    - pre);
      float dim = s_kg[r][d+32]* (s_yt[cur][r][d+32] - pim);
      s_x[r][d]    = pre + dre;
      s_x[r][d+32] = pim + dim;
      s_upd[r][d]    = dre;
      s_upd[r][d+32] = dim;
    }
    __syncthreads();
  }

  // ======================= ROLLOUT: 32 steps =======================
  #pragma unroll 1
  for (int u=0; u<WOUT; ++u){
    // gates: x = [h_r (256), curr (64)], gi K=320; gh K=256
    {
      const int j  = tid & 255;
      const int r0 = (tid >> 8) * 4;
      float a_ir[4]={0,0,0,0}, a_iz[4]={0,0,0,0}, a_in[4]={0,0,0,0};
      float a_hr[4]={0,0,0,0}, a_hz[4]={0,0,0,0}, a_hn[4]={0,0,0,0};
      const float4* tir = (const float4*)t_wihr;
      const float4* thr_= (const float4*)t_whhr;
      #pragma unroll 2
      for (int k4=0;k4<64;k4++){
        float4 wir = tir[k4*768 +       j];
        float4 wiz = tir[k4*768 + 256 + j];
        float4 win = tir[k4*768 + 512 + j];
        float4 whr = thr_[k4*768 +       j];
        float4 whz = thr_[k4*768 + 256 + j];
        float4 whn = thr_[k4*768 + 512 + j];
        #pragma unroll
        for (int ri=0;ri<4;ri++){
          float4 ah = *(const float4*)&s_h[r0+ri][k4<<2];
          fma4(a_ir[ri], ah, wir);
          fma4(a_iz[ri], ah, wiz);
          fma4(a_in[ri], ah, win);
          fma4(a_hr[ri], ah, whr);
          fma4(a_hz[ri], ah, whz);
          fma4(a_hn[ri], ah, whn);
        }
      }
      #pragma unroll 2
      for (int k4=64;k4<80;k4++){   // curr part of gi (K 256..319)
        float4 wir = tir[k4*768 +       j];
        float4 wiz = tir[k4*768 + 256 + j];
        float4 win = tir[k4*768 + 512 + j];
        #pragma unroll
        for (int ri=0;ri<4;ri++){
          float4 ax = *(const float4*)&s_x[r0+ri][(k4-64)<<2];
          fma4(a_ir[ri], ax, wir);
          fma4(a_iz[ri], ax, wiz);
          fma4(a_in[ri], ax, win);
        }
      }
      float bir=sb[OFF_BIHR+j], biz=sb[OFF_BIHR+256+j], bin=sb[OFF_BIHR+512+j];
      float bhr=sb[OFF_BHHR+j], bhz=sb[OFF_BHHR+256+j], bhn=sb[OFF_BHHR+512+j];
      #pragma unroll
      for (int ri=0;ri<4;ri++){
        float r_ = sigm(a_ir[ri]+bir + a_hr[ri]+bhr);
        float z_ = sigm(a_iz[ri]+biz + a_hz[ri]+bhz);
        float n_ = tanh_f(a_in[ri]+bin + r_*(a_hn[ri]+bhn));
        s_pre[r0+ri][j] = (1.f - z_)*n_ + z_*s_h[r0+ri][j];
      }
    }
    __syncthreads();

    ln_rp(OFF_WRPR, OFF_BRPR);
    __syncthreads();

    // rotate curr, emit (f32 output)
    if (tid < 256){
      int r = tid>>5, d = tid&31;
      float re = s_x[r][d], im = s_x[r][d+32];
      float rho = s_rho[r], phi = s_phi[r];
      float sn, cs; __sincosf(phi, &sn, &cs);
      float nre = rho*(cs*re - sn*im);
      float nim = rho*(sn*re + cs*im);
      s_x[r][d]    = nre;
      s_x[r][d+32] = nim;
      size_t ob = (size_t)(gb0+r)*(WOUT*64) + (size_t)u*64;
      out[ob + d]      = nre;
      out[ob + d + 32] = nim;
    }
    __syncthreads();
  }
}

extern "C" void kernel_launch(void* const* d_in, const int* in_sizes, int n_in,
                              void* d_out, int out_size, void* d_ws, size_t ws_size,
                              hipStream_t stream){
  const float* x_in = (const float*)d_in[0];
  // d_in[1] = w_out scalar (hardcoded 32)
  const float* Wf   = (const float*)d_in[2];
  const float* bf_  = (const float*)d_in[3];
  const float* Wih  = (const float*)d_in[4];
  const float* Whh  = (const float*)d_in[5];
  const float* bih  = (const float*)d_in[6];
  const float* bhh  = (const float*)d_in[7];
  const float* lng  = (const float*)d_in[8];
  const float* lnb  = (const float*)d_in[9];
  const float* Wg   = (const float*)d_in[10];
  const float* bg   = (const float*)d_in[11];
  const float* Wrp  = (const float*)d_in[12];
  const float* brp  = (const float*)d_in[13];
  const float* Wihr = (const float*)d_in[14];
  const float* Whhr = (const float*)d_in[15];
  const float* bihr = (const float*)d_in[16];
  const float* bhhr = (const float*)d_in[17];
  const float* Wrpr = (const float*)d_in[18];
  const float* brpr = (const float*)d_in[19];

  float* ws = (float*)d_ws;
  float* t_wf   = ws;             // 49152
  float* t_wih  = ws + 49152;     // 196608
  float* t_whh  = ws + 245760;    // 196608
  float* t_wg   = ws + 442368;    // 16384
  float* t_wihr = ws + 458752;    // 245760
  float* t_whhr = ws + 704512;    // 196608  (end: 901120 floats = 3.44 MB)

  transpose_w<<<(49152 +255)/256, 256, 0, stream>>>(Wf,   t_wf,   256, 192);
  transpose_w<<<(196608+255)/256, 256, 0, stream>>>(Wih,  t_wih,  768, 256);
  transpose_w<<<(196608+255)/256, 256, 0, stream>>>(Whh,  t_whh,  768, 256);
  transpose_w<<<(16384 +255)/256, 256, 0, stream>>>(Wg,   t_wg,   64,  256);
  transpose_w<<<(245760+255)/256, 256, 0, stream>>>(Wihr, t_wihr, 768, 320);
  transpose_w<<<(196608+255)/256, 256, 0, stream>>>(Whhr, t_whhr, 768, 256);

  knet_f32<<<128, 512, 0, stream>>>(x_in, t_wf, t_wih, t_whh, t_wg, t_wihr, t_whhr,
      bf_, bih, bhh, lng, lnb, bg, Wrp, brp, bihr, bhhr, Wrpr, brpr,
      (float*)d_out);
}

// Round 5
// 3256.285 us; speedup vs baseline: 1.9043x; 1.9043x over previous
//
#include <hip/hip_runtime.h>

#define QLEN 128
#define WOUT 32
#define ROWS 4
#define PI_F 3.14159265358979f

// ---- bias/small-weight LDS offsets (floats) ----
#define OFF_BF    0      // 256
#define OFF_BIH   256    // 768
#define OFF_BHH   1024   // 768
#define OFF_LNG   1792   // 256
#define OFF_LNB   2048   // 256
#define OFF_BG    2304   // 64
#define OFF_BRP   2368   // 2
#define OFF_BIHR  2370   // 768
#define OFF_BHHR  3138   // 768
#define OFF_BRPR  3906   // 2
#define OFF_WRP   3908   // 512 (Wrp[2][256])
#define OFF_WRPR  4420   // 512
#define SB_TOTAL  4932

__device__ __forceinline__ float sigm(float x){ return 1.0f/(1.0f + __expf(-x)); }
__device__ __forceinline__ float tanh_f(float x){ return 2.0f/(1.0f + __expf(-2.0f*x)) - 1.0f; }

// Repack f32 W[N][K] (row-major) -> f32 T[k/4][N][4] so a wave's float4 weight
// loads (lane -> consecutive col c) are fully coalesced.
__global__ void transpose_w(const float* __restrict__ src, float* __restrict__ dst, int N, int K){
  int i = blockIdx.x*blockDim.x + threadIdx.x;
  if (i < N*K){
    int c = i / K; int k = i - c*K;
    dst[(size_t)(((k>>2)*N + c)<<2) + (k&3)] = src[i];
  }
}

__device__ __forceinline__ void fma4(float& acc, const float4& a, const float4& w){
  acc = fmaf(a.x, w.x, acc);
  acc = fmaf(a.y, w.y, acc);
  acc = fmaf(a.z, w.z, acc);
  acc = fmaf(a.w, w.w, acc);
}

__global__ __launch_bounds__(1024) void knet_f32(
  const float* __restrict__ x_in,    // f32 [B][128][64]
  const float* __restrict__ t_wf,    // [48][256][4]
  const float* __restrict__ t_wih,   // [64][768][4]
  const float* __restrict__ t_whh,   // [64][768][4]
  const float* __restrict__ t_wg,    // [64][64][4]
  const float* __restrict__ t_wihr,  // [80][768][4]
  const float* __restrict__ t_whhr,  // [64][768][4]
  const float* __restrict__ p_bf,  const float* __restrict__ p_bih, const float* __restrict__ p_bhh,
  const float* __restrict__ p_lng, const float* __restrict__ p_lnb,
  const float* __restrict__ p_bg,  const float* __restrict__ p_wrp, const float* __restrict__ p_brp,
  const float* __restrict__ p_bihr,const float* __restrict__ p_bhhr,
  const float* __restrict__ p_wrpr,const float* __restrict__ p_brpr,
  float* __restrict__ out)           // f32 [B][32][64]
{
  __shared__ __align__(16) float sb[SB_TOTAL];
  __shared__ __align__(16) float s_h  [ROWS][260];   // post-LN h
  __shared__ __align__(16) float s_pre[ROWS][260];   // pre-LN GRU output
  __shared__ __align__(16) float s_zf [ROWS][260];
  __shared__ __align__(16) float s_feat[ROWS][196];
  __shared__ __align__(16) float s_x  [ROWS][64];    // x_post / curr (for rollout matmul)
  __shared__ __align__(16) float s_part[4][6][ROWS][256];  // k-split partials (98 KB)
  __shared__ float s_rho[ROWS], s_phi[ROWS];

  const int tid = threadIdx.x;
  const int gb0 = blockIdx.x * ROWS;

  // ---- preload biases / tiny weights into LDS ----
  if (tid<256){ sb[OFF_BF+tid]=p_bf[tid]; sb[OFF_LNG+tid]=p_lng[tid]; sb[OFF_LNB+tid]=p_lnb[tid]; }
  if (tid<768){ sb[OFF_BIH+tid]=p_bih[tid]; sb[OFF_BHH+tid]=p_bhh[tid]; sb[OFF_BIHR+tid]=p_bihr[tid]; sb[OFF_BHHR+tid]=p_bhhr[tid]; }
  if (tid<64)  sb[OFF_BG+tid]=p_bg[tid];
  if (tid<512){ sb[OFF_WRP+tid]=p_wrp[tid]; sb[OFF_WRPR+tid]=p_wrpr[tid]; }
  if (tid<2){ sb[OFF_BRP+tid]=p_brp[tid]; sb[OFF_BRPR+tid]=p_brpr[tid]; }
  if (tid>=768 && tid<768+ROWS*256){ int e=tid-768; s_h[e>>8][e&255]=0.f; }  // partial
  for (int e=tid; e<ROWS*256; e+=1024){ s_h[e>>8][e&255]=0.f; }              // full (cheap, idempotent)

  const int w    = tid >> 6;    // wave id 0..15
  const int lane = tid & 63;
  const int g4   = tid >> 8;    // k-split group 0..3
  const int j256 = tid & 255;

  // persistent per-thread state (threads 0..255): row pr, component pd
  const int pr = tid >> 6;      // valid when tid<256
  const int pd = tid & 63;
  float y_cur = 0.f, x_st = 0.f;
  if (tid < 256){
    y_cur = x_in[(size_t)(gb0+pr)*(QLEN*64) + pd];
    x_st  = y_cur;
    s_x[pr][pd] = x_st;
    s_feat[pr][pd] = 0.f; s_feat[pr][64+pd] = 0.f; s_feat[pr][128+pd] = 0.f;  // feat_0 = [0,0,0]
  }
  __syncthreads();

  // LayerNorm + readout-proj (rho/phi). reads s_pre, writes s_h, s_rho/s_phi. waves 0..3.
  auto ln_rp = [&](int wrpO, int brpO){
    if (w < ROWS){
      const int row = w;
      const int c0  = lane << 2;
      float4 v = *(const float4*)&s_pre[row][c0];
      float sum = v.x+v.y+v.z+v.w;
      float ss  = v.x*v.x + v.y*v.y + v.z*v.z + v.w*v.w;
      #pragma unroll
      for (int m=1;m<64;m<<=1){ sum += __shfl_xor(sum,m); ss += __shfl_xor(ss,m); }
      float mu = sum * (1.f/256.f);
      float rs = rsqrtf(ss*(1.f/256.f) - mu*mu + 1e-5f);
      float4 hn;
      hn.x = (v.x-mu)*rs*sb[OFF_LNG+c0  ] + sb[OFF_LNB+c0  ];
      hn.y = (v.y-mu)*rs*sb[OFF_LNG+c0+1] + sb[OFF_LNB+c0+1];
      hn.z = (v.z-mu)*rs*sb[OFF_LNG+c0+2] + sb[OFF_LNB+c0+2];
      hn.w = (v.w-mu)*rs*sb[OFF_LNG+c0+3] + sb[OFF_LNB+c0+3];
      *(float4*)&s_h[row][c0] = hn;
      float p0 = hn.x*sb[wrpO+c0] + hn.y*sb[wrpO+c0+1] + hn.z*sb[wrpO+c0+2] + hn.w*sb[wrpO+c0+3];
      float p1 = hn.x*sb[wrpO+256+c0] + hn.y*sb[wrpO+256+c0+1] + hn.z*sb[wrpO+256+c0+2] + hn.w*sb[wrpO+256+c0+3];
      #pragma unroll
      for (int m=1;m<64;m<<=1){ p0 += __shfl_xor(p0,m); p1 += __shfl_xor(p1,m); }
      if (lane==0){
        s_rho[row] = 1.25f * sigm(p0 + sb[brpO]);
        s_phi[row] = PI_F * tanh_f(p1 + sb[brpO+1]);
      }
    }
  };

  // ======================= ENCODER: 128 steps =======================
  #pragma unroll 1
  for (int t=0; t<QLEN; ++t){
    // B partial: zf-pre = feat @ Wf^T  (K=192, 4-way k-split: 12 k4 each)
    {
      float a0=0.f,a1=0.f,a2=0.f,a3=0.f;
      const float4* tf = (const float4*)t_wf;
      const int k0 = g4*12;
      #pragma unroll 2
      for (int k4=k0;k4<k0+12;k4++){
        float4 wv = tf[k4*256 + j256];
        float4 f0=*(const float4*)&s_feat[0][k4<<2];
        float4 f1=*(const float4*)&s_feat[1][k4<<2];
        float4 f2=*(const float4*)&s_feat[2][k4<<2];
        float4 f3=*(const float4*)&s_feat[3][k4<<2];
        fma4(a0,f0,wv); fma4(a1,f1,wv); fma4(a2,f2,wv); fma4(a3,f3,wv);
      }
      s_part[g4][0][0][j256]=a0; s_part[g4][0][1][j256]=a1;
      s_part[g4][0][2][j256]=a2; s_part[g4][0][3][j256]=a3;
    }
    __syncthreads();
    // B finalize: 1024 outputs, 1/thread
    {
      const int r=tid>>8, jj=tid&255;
      s_zf[r][jj] = tanh_f(s_part[0][0][r][jj]+s_part[1][0][r][jj]
                          +s_part[2][0][r][jj]+s_part[3][0][r][jj] + sb[OFF_BF+jj]);
    }
    __syncthreads();
    // C partial: 6 gates, K=256, 16 k4 per group
    {
      float a[6][ROWS];
      #pragma unroll
      for (int gg=0;gg<6;gg++){ a[gg][0]=0.f;a[gg][1]=0.f;a[gg][2]=0.f;a[gg][3]=0.f; }
      const float4* tih=(const float4*)t_wih;
      const float4* thh=(const float4*)t_whh;
      const int k0=g4*16;
      #pragma unroll 2
      for (int k4=k0;k4<k0+16;k4++){
        const int base=k4*768 + j256;
        float4 wir=tih[base], wiz=tih[base+256], win=tih[base+512];
        float4 whr=thh[base], whz=thh[base+256], whn=thh[base+512];
        #pragma unroll
        for (int ri=0;ri<ROWS;ri++){
          float4 az=*(const float4*)&s_zf[ri][k4<<2];
          float4 ah=*(const float4*)&s_h [ri][k4<<2];
          fma4(a[0][ri],az,wir); fma4(a[1][ri],az,wiz); fma4(a[2][ri],az,win);
          fma4(a[3][ri],ah,whr); fma4(a[4][ri],ah,whz); fma4(a[5][ri],ah,whn);
        }
      }
      #pragma unroll
      for (int gg=0;gg<6;gg++)
        #pragma unroll
        for (int ri=0;ri<ROWS;ri++)
          s_part[g4][gg][ri][j256]=a[gg][ri];
    }
    __syncthreads();
    // C finalize
    {
      const int r=tid>>8, jj=tid&255;
      float s0=s_part[0][0][r][jj]+s_part[1][0][r][jj]+s_part[2][0][r][jj]+s_part[3][0][r][jj];
      float s1=s_part[0][1][r][jj]+s_part[1][1][r][jj]+s_part[2][1][r][jj]+s_part[3][1][r][jj];
      float s2=s_part[0][2][r][jj]+s_part[1][2][r][jj]+s_part[2][2][r][jj]+s_part[3][2][r][jj];
      float s3=s_part[0][3][r][jj]+s_part[1][3][r][jj]+s_part[2][3][r][jj]+s_part[3][3][r][jj];
      float s4=s_part[0][4][r][jj]+s_part[1][4][r][jj]+s_part[2][4][r][jj]+s_part[3][4][r][jj];
      float s5=s_part[0][5][r][jj]+s_part[1][5][r][jj]+s_part[2][5][r][jj]+s_part[3][5][r][jj];
      float r_ = sigm(s0+sb[OFF_BIH+jj]     + s3+sb[OFF_BHH+jj]);
      float z_ = sigm(s1+sb[OFF_BIH+256+jj] + s4+sb[OFF_BHH+256+jj]);
      float n_ = tanh_f(s2+sb[OFF_BIH+512+jj] + r_*(s5+sb[OFF_BHH+512+jj]));
      s_pre[r][jj] = (1.f - z_)*n_ + z_*s_h[r][jj];
    }
    __syncthreads();
    // D: LayerNorm + rho/phi
    ln_rp(OFF_WRP, OFF_BRP);
    __syncthreads();
    // E partial: K = h @ Wg^T (K=256, N=64)
    {
      const int j6=tid&63, er=(tid>>6)&3;
      float acc=0.f;
      const float4* tg=(const float4*)t_wg;
      const int k0=g4*16;
      #pragma unroll 4
      for (int k4=k0;k4<k0+16;k4++){
        float4 wv=tg[k4*64+j6];
        float4 a=*(const float4*)&s_h[er][k4<<2];
        fma4(acc,a,wv);
      }
      s_part[g4][0][er][j6]=acc;
    }
    __syncthreads();
    // FA: Kalman gain finalize + rotate + update + next feat (registers, threads 0..255)
    if (tid < 256){
      float kg = sigm(s_part[0][0][pr][pd]+s_part[1][0][pr][pd]
                     +s_part[2][0][pr][pd]+s_part[3][0][pr][pd] + sb[OFF_BG+pd]);
      float rho=s_rho[pr], phi=s_phi[pr];
      float sn,cs; __sincosf(phi,&sn,&cs);
      float px = __shfl_xor(x_st,32);
      float pre = (pd<32) ? rho*(cs*x_st - sn*px) : rho*(sn*px + cs*x_st);
      float del = kg*(y_cur - pre);
      x_st = pre + del;
      s_x[pr][pd] = x_st;
      const int tn = (t+1<QLEN)? t+1 : QLEN-1;
      float y_next = x_in[(size_t)(gb0+pr)*(QLEN*64) + (size_t)tn*64 + pd];
      s_feat[pr][pd]      = y_next - y_cur;
      s_feat[pr][64+pd]   = y_next - x_st;
      s_feat[pr][128+pd]  = del;
      y_cur = y_next;
    }
    __syncthreads();
  }

  // ======================= ROLLOUT: 32 steps =======================
  #pragma unroll 1
  for (int u=0; u<WOUT; ++u){
    // gates partial: gi = [h,curr] @ Wihr^T (K=320, 20 k4/group), gh = h @ Whhr^T (K=256, 16/group)
    {
      float a[6][ROWS];
      #pragma unroll
      for (int gg=0;gg<6;gg++){ a[gg][0]=0.f;a[gg][1]=0.f;a[gg][2]=0.f;a[gg][3]=0.f; }
      const float4* tir=(const float4*)t_wihr;
      const float4* th2=(const float4*)t_whhr;
      if (g4 < 3){
        const int k0=g4*20;
        #pragma unroll 2
        for (int k4=k0;k4<k0+20;k4++){
          const int base=k4*768 + j256;
          float4 wir=tir[base], wiz=tir[base+256], win=tir[base+512];
          #pragma unroll
          for (int ri=0;ri<ROWS;ri++){
            float4 ah=*(const float4*)&s_h[ri][k4<<2];
            fma4(a[0][ri],ah,wir); fma4(a[1][ri],ah,wiz); fma4(a[2][ri],ah,win);
          }
        }
      } else {
        #pragma unroll 2
        for (int k4=60;k4<64;k4++){
          const int base=k4*768 + j256;
          float4 wir=tir[base], wiz=tir[base+256], win=tir[base+512];
          #pragma unroll
          for (int ri=0;ri<ROWS;ri++){
            float4 ah=*(const float4*)&s_h[ri][k4<<2];
            fma4(a[0][ri],ah,wir); fma4(a[1][ri],ah,wiz); fma4(a[2][ri],ah,win);
          }
        }
        #pragma unroll 2
        for (int k4=64;k4<80;k4++){
          const int base=k4*768 + j256;
          float4 wir=tir[base], wiz=tir[base+256], win=tir[base+512];
          #pragma unroll
          for (int ri=0;ri<ROWS;ri++){
            float4 ax=*(const float4*)&s_x[ri][(k4-64)<<2];
            fma4(a[0][ri],ax,wir); fma4(a[1][ri],ax,wiz); fma4(a[2][ri],ax,win);
          }
        }
      }
      {
        const int k0=g4*16;
        #pragma unroll 2
        for (int k4=k0;k4<k0+16;k4++){
          const int base=k4*768 + j256;
          float4 whr=th2[base], whz=th2[base+256], whn=th2[base+512];
          #pragma unroll
          for (int ri=0;ri<ROWS;ri++){
            float4 ah=*(const float4*)&s_h[ri][k4<<2];
            fma4(a[3][ri],ah,whr); fma4(a[4][ri],ah,whz); fma4(a[5][ri],ah,whn);
          }
        }
      }
      #pragma unroll
      for (int gg=0;gg<6;gg++)
        #pragma unroll
        for (int ri=0;ri<ROWS;ri++)
          s_part[g4][gg][ri][j256]=a[gg][ri];
    }
    __syncthreads();
    // finalize
    {
      const int r=tid>>8, jj=tid&255;
      float s0=s_part[0][0][r][jj]+s_part[1][0][r][jj]+s_part[2][0][r][jj]+s_part[3][0][r][jj];
      float s1=s_part[0][1][r][jj]+s_part[1][1][r][jj]+s_part[2][1][r][jj]+s_part[3][1][r][jj];
      float s2=s_part[0][2][r][jj]+s_part[1][2][r][jj]+s_part[2][2][r][jj]+s_part[3][2][r][jj];
      float s3=s_part[0][3][r][jj]+s_part[1][3][r][jj]+s_part[2][3][r][jj]+s_part[3][3][r][jj];
      float s4=s_part[0][4][r][jj]+s_part[1][4][r][jj]+s_part[2][4][r][jj]+s_part[3][4][r][jj];
      float s5=s_part[0][5][r][jj]+s_part[1][5][r][jj]+s_part[2][5][r][jj]+s_part[3][5][r][jj];
      float r_ = sigm(s0+sb[OFF_BIHR+jj]     + s3+sb[OFF_BHHR+jj]);
      float z_ = sigm(s1+sb[OFF_BIHR+256+jj] + s4+sb[OFF_BHHR+256+jj]);
      float n_ = tanh_f(s2+sb[OFF_BIHR+512+jj] + r_*(s5+sb[OFF_BHHR+512+jj]));
      s_pre[r][jj] = (1.f - z_)*n_ + z_*s_h[r][jj];
    }
    __syncthreads();
    ln_rp(OFF_WRPR, OFF_BRPR);
    __syncthreads();
    // emit: rotate curr (registers + shfl), write out + s_x
    if (tid < 256){
      float rho=s_rho[pr], phi=s_phi[pr];
      float sn,cs; __sincosf(phi,&sn,&cs);
      float px = __shfl_xor(x_st,32);
      float nx = (pd<32) ? rho*(cs*x_st - sn*px) : rho*(sn*px + cs*x_st);
      x_st = nx;
      s_x[pr][pd] = nx;
      out[(size_t)(gb0+pr)*(WOUT*64) + (size_t)u*64 + pd] = nx;
    }
    __syncthreads();
  }
}

extern "C" void kernel_launch(void* const* d_in, const int* in_sizes, int n_in,
                              void* d_out, int out_size, void* d_ws, size_t ws_size,
                              hipStream_t stream){
  const float* x_in = (const float*)d_in[0];
  // d_in[1] = w_out scalar (hardcoded 32)
  const float* Wf   = (const float*)d_in[2];
  const float* bf_  = (const float*)d_in[3];
  const float* Wih  = (const float*)d_in[4];
  const float* Whh  = (const float*)d_in[5];
  const float* bih  = (const float*)d_in[6];
  const float* bhh  = (const float*)d_in[7];
  const float* lng  = (const float*)d_in[8];
  const float* lnb  = (const float*)d_in[9];
  const float* Wg   = (const float*)d_in[10];
  const float* bg   = (const float*)d_in[11];
  const float* Wrp  = (const float*)d_in[12];
  const float* brp  = (const float*)d_in[13];
  const float* Wihr = (const float*)d_in[14];
  const float* Whhr = (const float*)d_in[15];
  const float* bihr = (const float*)d_in[16];
  const float* bhhr = (const float*)d_in[17];
  const float* Wrpr = (const float*)d_in[18];
  const float* brpr = (const float*)d_in[19];

  float* ws = (float*)d_ws;
  float* t_wf   = ws;             // 49152
  float* t_wih  = ws + 49152;     // 196608
  float* t_whh  = ws + 245760;    // 196608
  float* t_wg   = ws + 442368;    // 16384
  float* t_wihr = ws + 458752;    // 245760
  float* t_whhr = ws + 704512;    // 196608  (end: 901120 floats = 3.44 MB)

  transpose_w<<<(49152 +255)/256, 256, 0, stream>>>(Wf,   t_wf,   256, 192);
  transpose_w<<<(196608+255)/256, 256, 0, stream>>>(Wih,  t_wih,  768, 256);
  transpose_w<<<(196608+255)/256, 256, 0, stream>>>(Whh,  t_whh,  768, 256);
  transpose_w<<<(16384 +255)/256, 256, 0, stream>>>(Wg,   t_wg,   64,  256);
  transpose_w<<<(245760+255)/256, 256, 0, stream>>>(Wihr, t_wihr, 768, 320);
  transpose_w<<<(196608+255)/256, 256, 0, stream>>>(Whhr, t_whhr, 768, 256);

  knet_f32<<<256, 1024, 0, stream>>>(x_in, t_wf, t_wih, t_whh, t_wg, t_wihr, t_whhr,
      bf_, bih, bhh, lng, lnb, bg, Wrp, brp, bihr, bhhr, Wrpr, brpr,
      (float*)d_out);
}